// Round 2
// 5436.263 us; speedup vs baseline: 1.0699x; 1.0699x over previous
//
#include <hip/hip_runtime.h>
#include <hip/hip_bf16.h>

// Persistent LSTM, round 5. B=128,T=1024,V=256,H=512,G=2048.
// 8 batch groups (16 rows) x 8 WGs (64 h-elems = 256 gate rows) = 64 WGs, 256 thr.
// Protocol: proven r3 agent-scope atomics + sc1 LLC loads (no sc0 speculation).
// NEW vs r3:
//  - poll by 7 lanes/wave (lane<8, self-exempt), per-lane exit: 8x less flag
//    traffic on LLC, no post-poll barrier (all waves gate themselves)
//  - per-thread direct 8B h publish in cell phase (hstage LDS relay deleted),
//    out-store sunk below the vmcnt(0) so its drain is off the critical path
//  - staging LDS writes remapped to 4x16B @ 256B stride: conflict-free per
//    16-lane phase (was 8-way); global source offsets permuted identically
//  - group early-exit: t >= max(x_len) over group rows -> sync-free zero-fill

#define TT 1024
#define BB 128
#define HH 512
#define VV 256
#define NGP 8   // batch groups
#define GM 16   // batch rows per group
#define NWG 8   // WGs per group
#define NE 64   // h-elems per WG
#define FSTRIDE 32  // ints per flag (128 B line)

typedef __attribute__((ext_vector_type(8))) short short8;
typedef __attribute__((ext_vector_type(4))) float f32x4;
typedef unsigned long long u64;
typedef unsigned short u16;

__device__ __forceinline__ u16 f2bf(float f) {
  __hip_bfloat16 h = __float2bfloat16(f);
  return *reinterpret_cast<u16*>(&h);
}
__device__ __forceinline__ float sigm(float x) { return 1.0f / (1.0f + __expf(-x)); }
__device__ __forceinline__ float tanh_(float x) { return 1.0f - 2.0f / (1.0f + __expf(2.0f * x)); }

__global__ void lstm_init(const int* __restrict__ x, int* __restrict__ x_t,
                          unsigned int* __restrict__ hbuf0, int* __restrict__ flags) {
  int idx = blockIdx.x * 256 + threadIdx.x;   // 0..131071
  int t = idx >> 7, b = idx & 127;
  x_t[idx] = x[b * TT + t];                   // x_t[t][b]
  if (idx < (BB * HH / 2)) hbuf0[idx] = 0u;   // zero h slot 0 (128 KB bf16)
  if (idx < NGP * NWG * FSTRIDE) flags[idx] = 0;
}

__launch_bounds__(256, 1)
__global__ void lstm_persist(const int* __restrict__ x_t, const int* __restrict__ x_len,
                             const float* __restrict__ W_ih, const float* __restrict__ W_hh,
                             const float* __restrict__ b_ih, const float* __restrict__ b_hh,
                             float* __restrict__ out,
                             u16* __restrict__ hbuf,   // [2][128][512] bf16 bits
                             int* __restrict__ flags) { // [8][8][FSTRIDE]
  const int tid = threadIdx.x;
  const int wave = tid >> 6, lane = tid & 63;
  const int nn = lane & 15, quad = lane >> 4;
  const int g = blockIdx.x >> 3, ig = blockIdx.x & 7;

  __shared__ u16 hA[GM * 520];          // staged h slab 16x512, stride 520
  __shared__ float gates_s[GM * 260];   // [16 b][256 gate cols], stride 260
  __shared__ int gmax_s;

  // ---- persistent W_hh fragments: wave=q, subtile s, col nn ----
  short8 bw[4][16];
#pragma unroll
  for (int s = 0; s < 4; s++) {
    const float* src = W_hh + (size_t)(wave * HH + ig * NE + s * 16 + nn) * HH + quad * 8;
#pragma unroll
    for (int kt = 0; kt < 16; kt++) {
      const float* p = src + kt * 32;
      short8 v;
#pragma unroll
      for (int j = 0; j < 8; j++) v[j] = (short)f2bf(p[j]);
      bw[s][kt] = v;
    }
  }

  // ---- cell mapping: thread -> (bc = tid>>4, 4 elems at e4=(tid&15)*4) ----
  const int bc = tid >> 4, e4 = (tid & 15) * 4;
  const int bglob = g * GM + bc;
  const int xl = x_len[bglob];
  float bias[4][4];
#pragma unroll
  for (int q = 0; q < 4; q++)
#pragma unroll
    for (int j = 0; j < 4; j++) {
      int grow = q * HH + ig * NE + e4 + j;
      bias[q][j] = b_ih[grow] + b_hh[grow];
    }
  float cst[4] = {0.f, 0.f, 0.f, 0.f}, hst[4] = {0.f, 0.f, 0.f, 0.f};

  // group max seq len (same 16 rows for all 8 WGs of the group)
  if (tid == 0) gmax_s = 1;
  __syncthreads();
  if ((tid & 15) == 0) atomicMax(&gmax_s, xl);

  // stage map: thread -> row tid>>4, 4 x 16B chunks at byte sc16*16 + k*256.
  // Per 16-lane LDS phase: span index (sc16 + 16k) % 8 = sc16 % 8 -> 8 spans
  // x 2 lanes = conflict-free (old 64B-contiguous layout was 8-way).
  const int srow = tid >> 4, sc16 = tid & 15;
  const u64 stage_off = (u64)((size_t)(g * GM + srow) * HH * 2 + (size_t)sc16 * 16);

  int* flmine = flags + (g * NWG + ig) * FSTRIDE;

  __syncthreads();
  const int gmax = gmax_s;

  for (int t = 0; t < gmax; ++t) {
    const int slot = t & 1;

    // prefetchable per-step inputs (fly during poll)
    const int xv = x_t[t * BB + bglob];
    float w[4][4];
#pragma unroll
    for (int q = 0; q < 4; q++)
#pragma unroll
      for (int j = 0; j < 4; j++)
        w[q][j] = W_ih[(size_t)(q * HH + ig * NE + e4 + j) * VV + xv];

    // 1. poll (7 lanes per wave, per-lane exit, self-exempt; no barrier after:
    //    each wave gates itself, hA writes are 2 barriers from last hA read)
    if (lane < 8 && lane != ig) {
      const int* fp = flags + (g * NWG + lane) * FSTRIDE;
      while (__hip_atomic_load(fp, __ATOMIC_RELAXED, __HIP_MEMORY_SCOPE_AGENT) < t)
        __builtin_amdgcn_s_sleep(1);
    }

    // 2. stage h slab (16 x 512 bf16 = 16 KB) LLC -> LDS via sc1 loads
    {
      u64 gsrc = (u64)(hbuf + (size_t)slot * (BB * HH)) + stage_off;
      short8 t0, t1, t2, t3;
      asm volatile(
          "global_load_dwordx4 %0, %4, off sc1\n\t"
          "global_load_dwordx4 %1, %4, off offset:256 sc1\n\t"
          "global_load_dwordx4 %2, %4, off offset:512 sc1\n\t"
          "global_load_dwordx4 %3, %4, off offset:768 sc1\n\t"
          "s_waitcnt vmcnt(0)"
          : "=&v"(t0), "=&v"(t1), "=&v"(t2), "=&v"(t3)
          : "v"(gsrc)
          : "memory");
      short8* dst = (short8*)(hA + srow * 520 + sc16 * 8);
      dst[0] = t0; dst[16] = t1; dst[32] = t2; dst[48] = t3;
    }
    __syncthreads();

    // 3. gates = h @ W_hh_slice^T : M=16, N=64 (4 subtiles), K=512 per wave
    {
      f32x4 acc[4] = {{0,0,0,0},{0,0,0,0},{0,0,0,0},{0,0,0,0}};
      const u16* ap = hA + nn * 520 + quad * 8;
#pragma unroll
      for (int kt = 0; kt < 16; kt++) {
        short8 a = *(const short8*)(ap + kt * 32);
#pragma unroll
        for (int s = 0; s < 4; s++)
          acc[s] = __builtin_amdgcn_mfma_f32_16x16x32_bf16(a, bw[s][kt], acc[s], 0, 0, 0);
      }
#pragma unroll
      for (int s = 0; s < 4; s++)
#pragma unroll
        for (int r = 0; r < 4; r++)
          gates_s[(quad * 4 + r) * 260 + wave * NE + s * 16 + nn] = acc[s][r];
    }
    __syncthreads();

    // 4. cell update: 4 cells per thread, fp32; per-thread direct h publish
    {
      f32x4 G0 = *(const f32x4*)&gates_s[bc * 260 + 0 * NE + e4];
      f32x4 G1 = *(const f32x4*)&gates_s[bc * 260 + 1 * NE + e4];
      f32x4 G2 = *(const f32x4*)&gates_s[bc * 260 + 2 * NE + e4];
      f32x4 G3 = *(const f32x4*)&gates_s[bc * 260 + 3 * NE + e4];
      const bool act = (t < xl);
      f32x4 outv;
#pragma unroll
      for (int j = 0; j < 4; j++) {
        float gi = G0[j] + w[0][j] + bias[0][j];
        float gf = G1[j] + w[1][j] + bias[1][j];
        float gg = G2[j] + w[2][j] + bias[2][j];
        float go = G3[j] + w[3][j] + bias[3][j];
        float iv = sigm(gi), fv = sigm(gf), gv = tanh_(gg), ov = sigm(go);
        float cn = fv * cst[j] + iv * gv;
        float hn = ov * tanh_(cn);
        if (act) { cst[j] = cn; hst[j] = hn; }
        outv[j] = act ? hn : 0.0f;
      }
      u64 hword = (u64)f2bf(hst[0]) | ((u64)f2bf(hst[1]) << 16)
                | ((u64)f2bf(hst[2]) << 32) | ((u64)f2bf(hst[3]) << 48);
      u64* hdst = (u64*)(hbuf + (size_t)(slot ^ 1) * (BB * HH)
                         + (size_t)bglob * HH + ig * NE + e4);
      __hip_atomic_store(hdst, hword, __ATOMIC_RELAXED, __HIP_MEMORY_SCOPE_AGENT);
      asm volatile("s_waitcnt vmcnt(0)" ::: "memory");   // drain h publish only
      __builtin_nontemporal_store(outv,
          (f32x4*)&out[((size_t)bglob * TT + t) * HH + ig * NE + e4]);
    }
    __syncthreads();

    // 5. publish version t+1 (all 256 h stores drained before the barrier)
    if (tid == 0)
      __hip_atomic_store(flmine, t + 1, __ATOMIC_RELAXED, __HIP_MEMORY_SCOPE_AGENT);
  }

  // sync-free zero-fill for t >= gmax (h frozen, outputs are PAD_VALUE=0)
  {
    f32x4 z = {0.f, 0.f, 0.f, 0.f};
    for (int t = gmax; t < TT; ++t)
      __builtin_nontemporal_store(z,
          (f32x4*)&out[((size_t)bglob * TT + t) * HH + ig * NE + e4]);
  }

  // finals: h_T, c_T (fp32), 4 elems per thread
  {
    f32x4 hv, cv;
#pragma unroll
    for (int j = 0; j < 4; j++) { hv[j] = hst[j]; cv[j] = cst[j]; }
    *(f32x4*)&out[(size_t)BB * TT * HH + (size_t)bglob * HH + ig * NE + e4] = hv;
    *(f32x4*)&out[(size_t)BB * TT * HH + (size_t)BB * HH + (size_t)bglob * HH + ig * NE + e4] = cv;
  }
}

extern "C" void kernel_launch(void* const* d_in, const int* in_sizes, int n_in,
                              void* d_out, int out_size, void* d_ws, size_t ws_size,
                              hipStream_t stream) {
  const int*   x     = (const int*)d_in[0];
  const int*   x_len = (const int*)d_in[1];
  const float* W_ih  = (const float*)d_in[2];
  const float* W_hh  = (const float*)d_in[3];
  const float* b_ih  = (const float*)d_in[4];
  const float* b_hh  = (const float*)d_in[5];
  float* out = (float*)d_out;

  char* ws = (char*)d_ws;
  int* x_t = (int*)ws;                            // 524288 B
  u16* hbuf = (u16*)(ws + 524288);                // 262144 B (2 slots)
  int* flags = (int*)(ws + 524288 + 262144);      // 8 KB (64 flags on own lines)

  lstm_init<<<512, 256, 0, stream>>>(x, x_t, (unsigned int*)hbuf, flags);
  lstm_persist<<<64, 256, 0, stream>>>(x_t, x_len, W_ih, W_hh, b_ih, b_hh, out, hbuf, flags);
}